// Round 7
// baseline (2557.822 us; speedup 1.0000x reference)
//
#include <hip/hip_runtime.h>

#define T_STEPS 63
#define NWG 256
#define WG_SIZE 256
#define NA 32
#define NV 224
#define NJC 14   // vocab j-chunks (2304 words each); group = 16 consecutive vocab WGs
#define NDC 16   // d-chunks (32 cols each)

typedef float floatx4 __attribute__((ext_vector_type(4)));
typedef __bf16 bf16x8 __attribute__((ext_vector_type(8)));

__device__ __forceinline__ unsigned short f2bf(float x) {
  unsigned int u = __builtin_bit_cast(unsigned int, x);
  u += 0x7fffu + ((u >> 16) & 1u);
  return (unsigned short)(u >> 16);
}
__device__ __forceinline__ float sigmoidf(float x) {
  return 1.0f / (1.0f + __expf(-x));
}
__device__ __forceinline__ floatx4 mfma_bf16(bf16x8 a, bf16x8 b, floatx4 c) {
  return __builtin_amdgcn_mfma_f32_16x16x32_bf16(a, b, c, 0, 0, 0);
}
__device__ __forceinline__ floatx4 mfma_fp8(long a, long b, floatx4 c) {
  return __builtin_amdgcn_mfma_f32_16x16x32_fp8_fp8(a, b, c, 0, 0, 0);
}
__device__ __forceinline__ unsigned char f2fp8(float x) {
  return (unsigned char)(__builtin_amdgcn_cvt_pk_fp8_f32(x, x, 0, false) & 0xff);
}

// ---- device-scope (MALL) relaxed atomics ----
__device__ __forceinline__ unsigned long long ald64(const void* p) {
  return __hip_atomic_load((const unsigned long long*)p, __ATOMIC_RELAXED, __HIP_MEMORY_SCOPE_AGENT);
}
__device__ __forceinline__ float aldf(const float* p) {
  return __hip_atomic_load(p, __ATOMIC_RELAXED, __HIP_MEMORY_SCOPE_AGENT);
}
__device__ __forceinline__ int aldi(const int* p) {
  return __hip_atomic_load(p, __ATOMIC_RELAXED, __HIP_MEMORY_SCOPE_AGENT);
}
__device__ __forceinline__ void astf(float* p, float v) {
  __hip_atomic_store(p, v, __ATOMIC_RELAXED, __HIP_MEMORY_SCOPE_AGENT);
}
__device__ __forceinline__ void asti(int* p, int v) {
  __hip_atomic_store(p, v, __ATOMIC_RELAXED, __HIP_MEMORY_SCOPE_AGENT);
}
__device__ __forceinline__ void astu16(unsigned short* p, unsigned short v) {
  __hip_atomic_store(p, v, __ATOMIC_RELAXED, __HIP_MEMORY_SCOPE_AGENT);
}
__device__ __forceinline__ void astu32(unsigned int* p, unsigned int v) {
  __hip_atomic_store(p, v, __ATOMIC_RELAXED, __HIP_MEMORY_SCOPE_AGENT);
}
__device__ __forceinline__ void astu8(unsigned char* p, unsigned char v) {
  __hip_atomic_store(p, v, __ATOMIC_RELAXED, __HIP_MEMORY_SCOPE_AGENT);
}
__device__ __forceinline__ void afaddf(float* p, float v) {
  __hip_atomic_fetch_add(p, v, __ATOMIC_RELAXED, __HIP_MEMORY_SCOPE_AGENT);
}
__device__ __forceinline__ bf16x8 ld_bf8_at(const void* p) {
  union { unsigned long long q[2]; bf16x8 v; } u;
  u.q[0] = ald64(p);
  u.q[1] = ald64((const char*)p + 8);
  return u.v;
}

// wave-parallel stamp check: lane i polls stamp[i] (i<n); whole wave proceeds when
// all n stamps >= tgt.
__device__ __forceinline__ void wave_spin(const int* base, int n, int tgt) {
  const int lane = threadIdx.x & 63;
  int v;
  do {
    v = (lane < n) ? aldi(base + lane) : 0x7fffffff;
  } while (__any(v < tgt));
}
// drain own vmem, then publish own stamp slot (plain store, single writer)
__device__ __forceinline__ void stamp_publish(int* slot, int v) {
  __builtin_amdgcn_s_waitcnt(0);
  __syncthreads();
  if (threadIdx.x == 0) asti(slot, v);
}

// ---- prologue: tiled transpose fp32 -> bf16 ----
__global__ void k_transpose(const float* __restrict__ in, unsigned short* __restrict__ out,
                            int R, int C, int ostride, int ooff) {
  __shared__ unsigned short tile[64][65];
  const int r0 = blockIdx.x << 6, c0 = blockIdx.y << 6;
  const int t = threadIdx.x;
  const int tr4 = t >> 6, tc = t & 63;
#pragma unroll
  for (int p = 0; p < 16; ++p) {
    int i = (p << 2) + tr4;
    int r = r0 + i;
    unsigned short v = 0;
    if (r < R) v = f2bf(in[(size_t)r * C + (c0 + tc)]);
    tile[i][tc] = v;
  }
  __syncthreads();
#pragma unroll
  for (int p = 0; p < 16; ++p) {
    int j = (p << 2) + tr4;
    int r = r0 + tc;
    if (r < R) out[(size_t)(c0 + j) * ostride + ooff + r] = tile[tc][j];
  }
}

// ---- prologue: tiled transpose fp32 -> fp8 ----
__global__ void k_transpose_fp8(const float* __restrict__ in, unsigned char* __restrict__ out,
                                int R, int C, long OS) {
  __shared__ unsigned char tile[64][68];
  const int r0 = blockIdx.x << 6, c0 = blockIdx.y << 6;
  const int t = threadIdx.x;
  const int tr4 = t >> 6, tc = t & 63;
#pragma unroll
  for (int p = 0; p < 16; ++p) {
    int i = (p << 2) + tr4;
    int r = r0 + i;
    float v = (r < R) ? in[(size_t)r * C + (c0 + tc)] : 0.f;
    tile[i][tc] = f2fp8(v);
  }
  __syncthreads();
#pragma unroll
  for (int p = 0; p < 16; ++p) {
    int j = (p << 2) + tr4;
    out[(size_t)(c0 + j) * OS + r0 + tc] = tile[tc][j];
  }
}

// ---- prologue: cs_bf[32][160] = bf16(content|style|pad0); out[:,0,:] = E[0] ----
__global__ void k_init(const float* __restrict__ content, const float* __restrict__ style,
                       const float* __restrict__ E, unsigned short* cs_bf, float* out) {
  const int stride = gridDim.x * blockDim.x;
  const int idx = blockIdx.x * blockDim.x + threadIdx.x;
  for (int i = idx; i < 32 * 160; i += stride) {
    int b = i / 160, k = i - b * 160;
    float v = 0.f;
    if (k < 128)      v = content[b * 128 + k];
    else if (k < 144) v = style[b * 16 + (k - 128)];
    cs_bf[i] = f2bf(v);
  }
  for (int i = idx; i < 32 * 512; i += stride) {
    int b = i >> 9, d = i & 511;
    out[(size_t)b * (64 * 512) + d] = E[d];
  }
}

// LDS layout (byte offsets), per-WG role:
//  vocab WG (wg>=32): Ws8   @0       [144][512] fp8, 8B-group XOR-swizzled by (row&7)
//                     E8TS  @73728   [32][2304] fp8 slice, 8B-group rotated by row
//                     e_lds @147456  [32][160]  fp8
//  A WG (wg<32):      wkr   @0       [64][1192] bf16
//                     zbuf  @152576  [4][32][16] f32
#define SMEM_BYTES 160768
#define OFF_E8TS_L 73728
#define OFF_ELDS_L 147456
#define OFF_ZBUF_L 152576

__global__ void __launch_bounds__(WG_SIZE, 1) k_main(
    const float* __restrict__ bvec,          // [2048]
    const float* __restrict__ bs,            // [32000]
    const unsigned char* __restrict__ Ws8_g, // [32256][512] fp8 (Ws^T)
    const unsigned char* __restrict__ E8T_g, // [512][32768]  fp8 (E^T)
    const unsigned short* __restrict__ WkrT, // [2048][1184]  bf16
    const unsigned short* __restrict__ cs_bf,// [32][160] bf16
    const float* __restrict__ E,             // [32000][512] fp32 (row 0 at s=0)
    unsigned short* hbr,     // [4][32][512] bf16 h replicas (A-side precompute)
    unsigned char* h8rep,    // [14][32][512] fp8 h replicas (one per jc group)
    unsigned short* embr,    // [4][32][512] bf16 emb replicas (A-side)
    unsigned char* e8g,      // [32][32768] fp8 e (softmax numerator)
    float* Upart,            // [NDC][NJC][32][32] f32 PV partials (plain stores)
    float* Zbuf,             // [2][NJC][32] f32 denominators (atomic, parity)
    int* hstep,              // [32]  A-WG w: h(s) published  -> s+1
    int* estep,              // [32]  A-WG w: emb(s) published -> s+1
    int* qstep,              // [NJC*16] vocab WG: e-slice(s) published -> s+1
    int* pvstep,             // [NDC][16] (jc slot 0..13): Upart(s) published -> s+1
    float* out)
{
  const int wg = blockIdx.x;
  const int t  = threadIdx.x;
  const int wv = t >> 6;
  const int lane = t & 63;
  const int q = lane >> 4;
  const int m16 = lane & 15;

  __shared__ __align__(16) char smem[SMEM_BYTES];
  unsigned char* lds_ws   = (unsigned char*)smem;
  unsigned char* lds_e8ts = (unsigned char*)(smem + OFF_E8TS_L);
  unsigned char* lds_e    = (unsigned char*)(smem + OFF_ELDS_L);
  unsigned short* lds_wkr = (unsigned short*)smem;
  float* zbuf = (float*)(smem + OFF_ZBUF_L);

  if (wg < NA) {
    // ---------------- A-WG: LSTM owner of d-slice [wg*16, wg*16+16) ----------------
    for (int idx = t; idx < 64 * 148; idx += WG_SIZE) {
      int row = idx / 148, grp = idx - row * 148;
      int g = row >> 4, c = row & 15;
      int n = g * 512 + (wg << 4) + c;
      ulong2 v = *(const ulong2*)(WkrT + (size_t)n * 1184 + grp * 8);
      *(ulong2*)((char*)lds_wkr + row * 2384 + grp * 16) = v;
    }
    const int dl = t & 15;
    const float bias0 = bvec[0 * 512 + (wg << 4) + dl];
    const float bias1 = bvec[1 * 512 + (wg << 4) + dl];
    const float bias2 = bvec[2 * 512 + (wg << 4) + dl];
    const float bias3 = bvec[3 * 512 + (wg << 4) + dl];
    float c2[2] = {0.f, 0.f};
    __syncthreads();

    const int mt = wv & 1, g0w = (wv >> 1) << 1;
    const int row = mt * 16 + m16;
    const unsigned short* b0row = lds_wkr + (g0w * 16 + m16) * 1192;
    const unsigned short* b1row = lds_wkr + ((g0w + 1) * 16 + m16) * 1192;
    const int d = (wg << 4) + dl;
    const int dc_a = wg >> 1;                 // d-chunk this slice lives in
    const int dl32 = ((wg & 1) << 4) + dl;    // col within the 32-wide chunk
    const int rpa = wg >> 3;                  // A-side replica this WG reads

    floatx4 accG0 = {0.f, 0.f, 0.f, 0.f}, accG1 = {0.f, 0.f, 0.f, 0.f};

    for (int s = 0; s < T_STEPS; ++s) {
      const int pc = s & 1;
      if (s == 0) {
        // cs-part
#pragma unroll
        for (int ks = 16; ks < 21; ++ks) {
          bf16x8 a = *(const bf16x8*)(cs_bf + row * 160 + (ks - 16) * 32 + q * 8);
          accG0 = mfma_bf16(a, *(const bf16x8*)(b0row + ks * 32 + q * 8), accG0);
          accG1 = mfma_bf16(a, *(const bf16x8*)(b1row + ks * 32 + q * 8), accG1);
        }
        // emb from E row 0
#pragma unroll 4
        for (int ks = 0; ks < 16; ++ks) {
          const float* ep = E + ks * 32 + q * 8;
          bf16x8 a;
#pragma unroll
          for (int i = 0; i < 8; ++i) a[i] = (__bf16)ep[i];
          accG0 = mfma_bf16(a, *(const bf16x8*)(b0row + ks * 32 + q * 8), accG0);
          accG1 = mfma_bf16(a, *(const bf16x8*)(b1row + ks * 32 + q * 8), accG1);
        }
      } else {
        // all A-WGs published emb(s-1)? (acc holds h+cs parts from precompute)
        wave_spin(estep, NA, s);
#pragma unroll 8
        for (int ks = 0; ks < 16; ++ks) {
          bf16x8 a = ld_bf8_at(embr + rpa * 16384 + row * 512 + ks * 32 + q * 8);
          accG0 = mfma_bf16(a, *(const bf16x8*)(b0row + ks * 32 + q * 8), accG0);
          accG1 = mfma_bf16(a, *(const bf16x8*)(b1row + ks * 32 + q * 8), accG1);
        }
      }
      // --- exchange z via LDS (wave owns (gate-pair, m-tile)) ---
#pragma unroll
      for (int r = 0; r < 4; ++r) {
        zbuf[(g0w * 32 + mt * 16 + q * 4 + r) * 16 + m16] = accG0[r];
        zbuf[((g0w + 1) * 32 + mt * 16 + q * 4 + r) * 16 + m16] = accG1[r];
      }
      __syncthreads();
      // --- LSTM pointwise; stage h to replicas (fire-and-forget stores) ---
#pragma unroll
      for (int pp = 0; pp < 2; ++pp) {
        const int b = (pp * 256 + t) >> 4;
        float zi = zbuf[(0 * 32 + b) * 16 + dl] + bias0;
        float zf = zbuf[(1 * 32 + b) * 16 + dl] + bias1;
        float zg = zbuf[(2 * 32 + b) * 16 + dl] + bias2;
        float zo = zbuf[(3 * 32 + b) * 16 + dl] + bias3;
        float iv = sigmoidf(zi), fv = sigmoidf(zf);
        float gv = tanhf(zg),    ov = sigmoidf(zo);
        c2[pp] = fv * c2[pp] + iv * gv;
        float h = ov * tanhf(c2[pp]);
        const unsigned short hb = f2bf(h);
        const unsigned char h8v = f2fp8(h);
#pragma unroll
        for (int rpl = 0; rpl < 4; ++rpl)
          astu16(hbr + rpl * 16384 + b * 512 + d, hb);
#pragma unroll
        for (int rpl = 0; rpl < NJC; ++rpl)
          astu8(h8rep + rpl * 16384 + b * 512 + d, h8v);
      }
      stamp_publish(hstep + wg, s + 1);   // single-writer slot
      // --- precompute h+cs part of z(s+1) (overlaps vocab logits+PV) ---
      if (s + 1 < T_STEPS) {
        wave_spin(hstep, NA, s + 1);      // all h(s) final
        accG0 = floatx4{0.f, 0.f, 0.f, 0.f};
        accG1 = floatx4{0.f, 0.f, 0.f, 0.f};
#pragma unroll 8
        for (int ks = 21; ks < 37; ++ks) {
          bf16x8 a = ld_bf8_at(hbr + rpa * 16384 + row * 512 + (ks - 21) * 32 + q * 8);
          accG0 = mfma_bf16(a, *(const bf16x8*)(b0row + ks * 32 + q * 8), accG0);
          accG1 = mfma_bf16(a, *(const bf16x8*)(b1row + ks * 32 + q * 8), accG1);
        }
#pragma unroll
        for (int ks = 16; ks < 21; ++ks) {
          bf16x8 a = *(const bf16x8*)(cs_bf + row * 160 + (ks - 16) * 32 + q * 8);
          accG0 = mfma_bf16(a, *(const bf16x8*)(b0row + ks * 32 + q * 8), accG0);
          accG1 = mfma_bf16(a, *(const bf16x8*)(b1row + ks * 32 + q * 8), accG1);
        }
      }
      // --- wait for the 14 PV partials covering our d-chunk ---
      wave_spin(pvstep + dc_a * 16, NJC, s + 1);
      // --- reduce 14 jc-partials + Z, normalize, publish emb replicas ---
      float evs[2];
#pragma unroll
      for (int pp = 0; pp < 2; ++pp) {
        const int b = (pp * 256 + t) >> 4;
        float uv = 0.f, Zv = 0.f;
        const float* up = Upart + ((size_t)(dc_a * NJC) * 32 + b) * 32 + dl32;
#pragma unroll
        for (int g = 0; g < NJC; ++g) uv += aldf(up + g * 1024);
#pragma unroll
        for (int g = 0; g < NJC; ++g) Zv += aldf(Zbuf + pc * (NJC * 32) + g * 32 + b);
        float ev = uv / Zv;
        evs[pp] = ev;
        const unsigned short evb = f2bf(ev);
#pragma unroll
        for (int rpl = 0; rpl < 4; ++rpl)
          astu16(embr + rpl * 16384 + b * 512 + d, evb);
      }
      // zero the Z parity consumed at step s-1 (all readers done: estep>=s observed)
      if (s >= 1 && t < NJC) astf(Zbuf + ((s - 1) & 1) * (NJC * 32) + t * 32 + wg, 0.0f);
      stamp_publish(estep + wg, s + 1);
      // --- deferred out stores (pure sink, off the critical chain) ---
#pragma unroll
      for (int pp = 0; pp < 2; ++pp) {
        const int b = (pp * 256 + t) >> 4;
        out[(size_t)b * (64 * 512) + (size_t)(s + 1) * 512 + d] = evs[pp];
      }
    }
  } else {
    // ---------------- vocab WG ----------------
    const int wgv = wg - NA;
    const int jc = wgv >> 4;          // j-chunk (2304 words)
    const int dc = wgv & 15;          // d-chunk (32 cols) this WG reduces in PV
    const long j0 = (long)wgv * 144;  // own 144-word logits slice
    const unsigned char* h8my = h8rep + jc * 16384;   // group-private h replica
    // Ws^T slice -> LDS
    for (int idx = t; idx < 144 * 64; idx += WG_SIZE) {
      int r2 = idx >> 6, grp = idx & 63;
      long v = *(const long*)(Ws8_g + (j0 + r2) * 512 + grp * 8);
      *(long*)(lds_ws + r2 * 512 + ((grp ^ (r2 & 7)) << 3)) = v;
    }
    // E^T slice [32 d][2304 j] -> LDS, rotated by d-row
    for (int idx = t; idx < 32 * 288; idx += WG_SIZE) {
      int dd = idx / 288, g = idx - dd * 288;
      long v = *(const long*)(E8T_g + (size_t)(dc * 32 + dd) * 32768 + (size_t)jc * 2304 + (size_t)g * 8);
      int g2 = g + dd; if (g2 >= 288) g2 -= 288;
      *(long*)(lds_e8ts + dd * 2304 + (g2 << 3)) = v;
    }
    for (int idx = t; idx < (32 * 160) / 8; idx += WG_SIZE) ((long*)lds_e)[idx] = 0;
    __syncthreads();

    for (int s = 0; s < T_STEPS; ++s) {
      wave_spin(hstep, NA, s + 1);      // all h(s) published
      const int pc = s & 1;
      long ah[2][16];
#pragma unroll
      for (int mtl = 0; mtl < 2; ++mtl)
#pragma unroll
        for (int ksr = 0; ksr < 16; ++ksr) {
          int ks = (ksr + jc) & 15;     // rotate read order by group
          ah[mtl][ks] = (long)ald64(h8my + (mtl * 16 + m16) * 512 + ks * 32 + q * 8);
        }
      // logits: 9 n-tiles round-robin over waves
      for (int tile = wv; tile < 9; tile += 4) {
        const int jl = tile * 16 + m16;
        const unsigned char* wrow = lds_ws + jl * 512;
        const int sw = jl & 7;
        floatx4 acc[2] = {{0,0,0,0},{0,0,0,0}};
#pragma unroll
        for (int ks = 0; ks < 16; ++ks) {
          int g = ks * 4 + q;
          long bfrag = *(const long*)(wrow + ((g ^ sw) << 3));
          acc[0] = mfma_fp8(ah[0][ks], bfrag, acc[0]);
          acc[1] = mfma_fp8(ah[1][ks], bfrag, acc[1]);
        }
        const long jg = j0 + jl;
        const float bsv = bs[jg < 32000 ? jg : 31999];
        const bool valid = (jg < 32000);
#pragma unroll
        for (int mtl = 0; mtl < 2; ++mtl)
#pragma unroll
          for (int r = 0; r < 4; ++r) {
            float e = valid ? __expf(acc[mtl][r] + bsv) : 0.0f;
            lds_e[(mtl * 16 + q * 4 + r) * 160 + jl] = f2fp8(e);
          }
      }
      __syncthreads();
      // publish e slice to global (coalesced 4B dwords)
      for (int idx = t; idx < 32 * 36; idx += WG_SIZE) {
        int b = idx / 36, g = idx - b * 36;
        unsigned int v = *(const unsigned int*)(lds_e + b * 160 + g * 4);
        astu32((unsigned int*)(e8g + (size_t)b * 32768 + j0 + g * 4), v);
      }
      // Z partial from the SAME fp8-rounded e (wave 3, lanes 0..31)
      if (t >= 192 && t < 224) {
        const int b = t - 192;
        const unsigned int* rowp = (const unsigned int*)(lds_e + b * 160);
        float z = 0.f;
        for (int g = 0; g < 36; ++g) {
          int w4 = (int)rowp[g];
          z += __builtin_amdgcn_cvt_f32_fp8(w4, 0) + __builtin_amdgcn_cvt_f32_fp8(w4, 1)
             + __builtin_amdgcn_cvt_f32_fp8(w4, 2) + __builtin_amdgcn_cvt_f32_fp8(w4, 3);
        }
        afaddf(Zbuf + pc * (NJC * 32) + jc * 32 + b, z);
      }
      stamp_publish(qstep + wgv, s + 1);
      // group readiness: 16 producers of chunk jc
      wave_spin(qstep + jc * 16, 16, s + 1);
      // --- PV: full partial e[:, jc-chunk] @ E[jc-chunk, dc*32..+32] ---
      // k-loop rotated by dc*4 so the 16 group members sweep disjoint phases
      {
        const int mtp = wv & 1, ntl = wv >> 1;
        const int dl_local = ntl * 16 + m16;
        const unsigned char* erow = lds_e8ts + dl_local * 2304;
        const unsigned char* arow = e8g + (size_t)(mtp * 16 + m16) * 32768 + (size_t)jc * 2304;
        floatx4 acc0 = {0,0,0,0}, acc1 = {0,0,0,0};
#pragma unroll 8
        for (int ii = 0; ii < 36; ++ii) {
          int ks = ((ii << 1) + (dc << 2)) % 72;     // even, pair-preserving
          long a0 = (long)ald64(arow + ks * 32 + q * 8);
          long a1 = (long)ald64(arow + (ks + 1) * 32 + q * 8);
          int g0i = ks * 4 + q + dl_local; if (g0i >= 288) g0i -= 288;
          int g1i = g0i + 4;               if (g1i >= 288) g1i -= 288;
          acc0 = mfma_fp8(a0, *(const long*)(erow + (g0i << 3)), acc0);
          acc1 = mfma_fp8(a1, *(const long*)(erow + (g1i << 3)), acc1);
        }
        floatx4 accs = acc0 + acc1;
#pragma unroll
        for (int r = 0; r < 4; ++r)
          astf(Upart + ((size_t)(dc * NJC + jc) * 32 + (mtp * 16 + (q << 2) + r)) * 32 + dl_local, accs[r]);
      }
      stamp_publish(pvstep + dc * 16 + jc, s + 1);
    }
  }
}

// ---------------- host ----------------
extern "C" void kernel_launch(void* const* d_in, const int* in_sizes, int n_in,
                              void* d_out, int out_size, void* d_ws, size_t ws_size,
                              hipStream_t stream) {
  const float* content = (const float*)d_in[0];
  const float* style   = (const float*)d_in[1];
  const float* E       = (const float*)d_in[2];
  const float* Wk      = (const float*)d_in[3];
  const float* Wr      = (const float*)d_in[4];
  const float* bvec    = (const float*)d_in[5];
  const float* Ws      = (const float*)d_in[6];
  const float* bs      = (const float*)d_in[7];
  float* out = (float*)d_out;
  char* ws = (char*)d_ws;

  constexpr size_t SZ_WS8  = 32256ull * 512;             // 16,515,072
  constexpr size_t SZ_E8T  = 512ull * 32768;             // 16,777,216
  constexpr size_t SZ_WKRT = 2048ull * 1184 * 2;         //  4,849,664
  constexpr size_t SZ_CS   = 32ull * 160 * 2;            //     10,240
  constexpr size_t SZ_HBR  = 4ull * 32 * 512 * 2;        //    131,072
  constexpr size_t SZ_H8R  = 14ull * 32 * 512;           //    229,376
  constexpr size_t SZ_EMBR = 4ull * 32 * 512 * 2;        //    131,072
  constexpr size_t SZ_E8G  = 32ull * 32768;              //  1,048,576
  constexpr size_t SZ_UP   = 16ull * 14 * 32 * 32 * 4;   //    917,504
  constexpr size_t SZ_ZB   = 2ull * NJC * 32 * 4;        //      3,584
  constexpr size_t SZ_HS   = 64ull * 4;                  //        256
  constexpr size_t SZ_ES   = 64ull * 4;                  //        256
  constexpr size_t SZ_QS   = 256ull * 4;                 //      1,024
  constexpr size_t SZ_PS   = 256ull * 4;                 //      1,024

  constexpr size_t OFF_WS8  = 0;
  constexpr size_t OFF_E8T  = OFF_WS8 + SZ_WS8;
  constexpr size_t OFF_WKRT = OFF_E8T + SZ_E8T;
  constexpr size_t OFF_CS   = OFF_WKRT + SZ_WKRT;
  constexpr size_t OFF_HBR  = OFF_CS + SZ_CS;
  constexpr size_t OFF_H8R  = OFF_HBR + SZ_HBR;
  constexpr size_t OFF_EMBR = OFF_H8R + SZ_H8R;
  constexpr size_t OFF_E8G  = OFF_EMBR + SZ_EMBR;
  constexpr size_t OFF_UP   = OFF_E8G + SZ_E8G;
  constexpr size_t OFF_ZB   = OFF_UP + SZ_UP;
  constexpr size_t OFF_HS   = OFF_ZB + SZ_ZB;
  constexpr size_t OFF_ES   = OFF_HS + SZ_HS;
  constexpr size_t OFF_QS   = OFF_ES + SZ_ES;
  constexpr size_t OFF_PS   = OFF_QS + SZ_QS;

  unsigned char*  Ws8_g = (unsigned char*)(ws + OFF_WS8);
  unsigned char*  E8T_g = (unsigned char*)(ws + OFF_E8T);
  unsigned short* WkrT  = (unsigned short*)(ws + OFF_WKRT);
  unsigned short* cs_bf = (unsigned short*)(ws + OFF_CS);
  unsigned short* hbr   = (unsigned short*)(ws + OFF_HBR);
  unsigned char*  h8rep = (unsigned char*)(ws + OFF_H8R);
  unsigned short* embr  = (unsigned short*)(ws + OFF_EMBR);
  unsigned char*  e8g   = (unsigned char*)(ws + OFF_E8G);
  float* Upart          = (float*)(ws + OFF_UP);
  float* Zbuf           = (float*)(ws + OFF_ZB);
  int* hstep            = (int*)(ws + OFF_HS);
  int* estep            = (int*)(ws + OFF_ES);
  int* qstep            = (int*)(ws + OFF_QS);
  int* pvstep           = (int*)(ws + OFF_PS);

  // zero state (ws poisoned each call)
  hipMemsetAsync(Ws8_g, 0, SZ_WS8, stream);
  hipMemsetAsync(E8T_g, 0, SZ_E8T, stream);
  hipMemsetAsync(WkrT, 0, SZ_WKRT, stream);
  hipMemsetAsync(ws + OFF_ZB, 0, SZ_ZB + SZ_HS + SZ_ES + SZ_QS + SZ_PS, stream);

  // transposed weight copies; Wkr k-layout = Wk(656) | pad16 | Wr(512)
  k_transpose_fp8<<<dim3(8, 500), 256, 0, stream>>>(Ws, Ws8_g, 512, 32000, 512);
  k_transpose_fp8<<<dim3(500, 8), 256, 0, stream>>>(E, E8T_g, 32000, 512, 32768);
  k_transpose<<<dim3(11, 32), 256, 0, stream>>>(Wk, WkrT, 656, 2048, 1184, 0);
  k_transpose<<<dim3(8, 32), 256, 0, stream>>>(Wr, WkrT, 512, 2048, 1184, 672);
  k_init<<<64, 256, 0, stream>>>(content, style, E, cs_bf, out);

  void* args[] = { (void*)&bvec, (void*)&bs, (void*)&Ws8_g, (void*)&E8T_g, (void*)&WkrT,
                   (void*)&cs_bf, (void*)&E, (void*)&hbr, (void*)&h8rep, (void*)&embr,
                   (void*)&e8g, (void*)&Upart, (void*)&Zbuf,
                   (void*)&hstep, (void*)&estep, (void*)&qstep, (void*)&pvstep,
                   (void*)&out };
  hipLaunchCooperativeKernel((void*)k_main, dim3(NWG), dim3(WG_SIZE), args, 0, stream);

  (void)in_sizes; (void)n_in; (void)out_size; (void)ws_size;
}

// Round 8
// 2088.260 us; speedup vs baseline: 1.2249x; 1.2249x over previous
//
#include <hip/hip_runtime.h>

#define T_STEPS 63
#define NWG 256
#define WG_SIZE 256
#define NA 32
#define NV 224
#define NJC 14   // vocab j-chunks (2304 words each); group = 16 consecutive vocab WGs
#define NDC 16   // d-chunks (32 cols each)

typedef float floatx4 __attribute__((ext_vector_type(4)));
typedef __bf16 bf16x8 __attribute__((ext_vector_type(8)));

__device__ __forceinline__ unsigned short f2bf(float x) {
  unsigned int u = __builtin_bit_cast(unsigned int, x);
  u += 0x7fffu + ((u >> 16) & 1u);
  return (unsigned short)(u >> 16);
}
__device__ __forceinline__ float sigmoidf(float x) {
  return 1.0f / (1.0f + __expf(-x));
}
__device__ __forceinline__ floatx4 mfma_bf16(bf16x8 a, bf16x8 b, floatx4 c) {
  return __builtin_amdgcn_mfma_f32_16x16x32_bf16(a, b, c, 0, 0, 0);
}
__device__ __forceinline__ floatx4 mfma_fp8(long a, long b, floatx4 c) {
  return __builtin_amdgcn_mfma_f32_16x16x32_fp8_fp8(a, b, c, 0, 0, 0);
}
__device__ __forceinline__ unsigned char f2fp8(float x) {
  return (unsigned char)(__builtin_amdgcn_cvt_pk_fp8_f32(x, x, 0, false) & 0xff);
}

// ---- device-scope (MALL) relaxed atomics ----
__device__ __forceinline__ unsigned long long ald64(const void* p) {
  return __hip_atomic_load((const unsigned long long*)p, __ATOMIC_RELAXED, __HIP_MEMORY_SCOPE_AGENT);
}
__device__ __forceinline__ float aldf(const float* p) {
  return __hip_atomic_load(p, __ATOMIC_RELAXED, __HIP_MEMORY_SCOPE_AGENT);
}
__device__ __forceinline__ int aldi(const int* p) {
  return __hip_atomic_load(p, __ATOMIC_RELAXED, __HIP_MEMORY_SCOPE_AGENT);
}
__device__ __forceinline__ void astf(float* p, float v) {
  __hip_atomic_store(p, v, __ATOMIC_RELAXED, __HIP_MEMORY_SCOPE_AGENT);
}
__device__ __forceinline__ void asti(int* p, int v) {
  __hip_atomic_store(p, v, __ATOMIC_RELAXED, __HIP_MEMORY_SCOPE_AGENT);
}
__device__ __forceinline__ void astu16(unsigned short* p, unsigned short v) {
  __hip_atomic_store(p, v, __ATOMIC_RELAXED, __HIP_MEMORY_SCOPE_AGENT);
}
__device__ __forceinline__ void astu32(unsigned int* p, unsigned int v) {
  __hip_atomic_store(p, v, __ATOMIC_RELAXED, __HIP_MEMORY_SCOPE_AGENT);
}
__device__ __forceinline__ void astu8(unsigned char* p, unsigned char v) {
  __hip_atomic_store(p, v, __ATOMIC_RELAXED, __HIP_MEMORY_SCOPE_AGENT);
}
__device__ __forceinline__ void afaddf(float* p, float v) {
  __hip_atomic_fetch_add(p, v, __ATOMIC_RELAXED, __HIP_MEMORY_SCOPE_AGENT);
}
__device__ __forceinline__ bf16x8 ld_bf8_at(const void* p) {
  union { unsigned long long q[2]; bf16x8 v; } u;
  u.q[0] = ald64(p);
  u.q[1] = ald64((const char*)p + 8);
  return u.v;
}

// wave-parallel stamp check: lane i polls stamp[i] (i<n); whole wave proceeds when
// all n stamps >= tgt.
__device__ __forceinline__ void wave_spin(const int* base, int n, int tgt) {
  const int lane = threadIdx.x & 63;
  int v;
  do {
    v = (lane < n) ? aldi(base + lane) : 0x7fffffff;
  } while (__any(v < tgt));
}
// drain own vmem, then publish own stamp slot (plain store, single writer)
__device__ __forceinline__ void stamp_publish(int* slot, int v) {
  __builtin_amdgcn_s_waitcnt(0);
  __syncthreads();
  if (threadIdx.x == 0) asti(slot, v);
}

// ---- prologue: tiled transpose fp32 -> bf16 ----
__global__ void k_transpose(const float* __restrict__ in, unsigned short* __restrict__ out,
                            int R, int C, int ostride, int ooff) {
  __shared__ unsigned short tile[64][65];
  const int r0 = blockIdx.x << 6, c0 = blockIdx.y << 6;
  const int t = threadIdx.x;
  const int tr4 = t >> 6, tc = t & 63;
#pragma unroll
  for (int p = 0; p < 16; ++p) {
    int i = (p << 2) + tr4;
    int r = r0 + i;
    unsigned short v = 0;
    if (r < R) v = f2bf(in[(size_t)r * C + (c0 + tc)]);
    tile[i][tc] = v;
  }
  __syncthreads();
#pragma unroll
  for (int p = 0; p < 16; ++p) {
    int j = (p << 2) + tr4;
    int r = r0 + tc;
    if (r < R) out[(size_t)(c0 + j) * ostride + ooff + r] = tile[tc][j];
  }
}

// ---- prologue: tiled transpose fp32 -> fp8 ----
__global__ void k_transpose_fp8(const float* __restrict__ in, unsigned char* __restrict__ out,
                                int R, int C, long OS) {
  __shared__ unsigned char tile[64][68];
  const int r0 = blockIdx.x << 6, c0 = blockIdx.y << 6;
  const int t = threadIdx.x;
  const int tr4 = t >> 6, tc = t & 63;
#pragma unroll
  for (int p = 0; p < 16; ++p) {
    int i = (p << 2) + tr4;
    int r = r0 + i;
    float v = (r < R) ? in[(size_t)r * C + (c0 + tc)] : 0.f;
    tile[i][tc] = f2fp8(v);
  }
  __syncthreads();
#pragma unroll
  for (int p = 0; p < 16; ++p) {
    int j = (p << 2) + tr4;
    out[(size_t)(c0 + j) * OS + r0 + tc] = tile[tc][j];
  }
}

// ---- prologue: cs_bf[32][160] = bf16(content|style|pad0); out[:,0,:] = E[0] ----
__global__ void k_init(const float* __restrict__ content, const float* __restrict__ style,
                       const float* __restrict__ E, unsigned short* cs_bf, float* out) {
  const int stride = gridDim.x * blockDim.x;
  const int idx = blockIdx.x * blockDim.x + threadIdx.x;
  for (int i = idx; i < 32 * 160; i += stride) {
    int b = i / 160, k = i - b * 160;
    float v = 0.f;
    if (k < 128)      v = content[b * 128 + k];
    else if (k < 144) v = style[b * 16 + (k - 128)];
    cs_bf[i] = f2bf(v);
  }
  for (int i = idx; i < 32 * 512; i += stride) {
    int b = i >> 9, d = i & 511;
    out[(size_t)b * (64 * 512) + d] = E[d];
  }
}

// LDS layout (byte offsets), per-WG role:
//  vocab WG (wg>=32): Ws8   @0       [144][512] fp8, 8B-group XOR-swizzled by (row&7)
//                     E8TS  @73728   [32][2304] fp8 slice, 8B-group rotated by row
//                     e_lds @147456  [32][160]  fp8
//  A WG (wg<32):      wkr   @0       [64][1192] bf16
//                     zbuf  @152576  [4][32][16] f32
#define SMEM_BYTES 160768
#define OFF_E8TS_L 73728
#define OFF_ELDS_L 147456
#define OFF_ZBUF_L 152576

__global__ void __launch_bounds__(WG_SIZE, 1) k_main(
    const float* __restrict__ bvec,          // [2048]
    const float* __restrict__ bs,            // [32000]
    const unsigned char* __restrict__ Ws8_g, // [32256][512] fp8 (Ws^T)
    const unsigned char* __restrict__ E8T_g, // [512][32768]  fp8 (E^T)
    const unsigned short* __restrict__ WkrT, // [2048][1184]  bf16
    const unsigned short* __restrict__ cs_bf,// [32][160] bf16
    const float* __restrict__ E,             // [32000][512] fp32 (row 0 at s=0)
    unsigned short* h_bufg,  // [32][512] bf16
    unsigned char* h8,       // [32][512] fp8
    unsigned short* emb_bf,  // [32][512] bf16 normalized soft embedding
    unsigned char* e8g,      // [32][32768] fp8 e (softmax numerator)
    float* Upart,            // [NDC][NJC][32][32] f32 PV partials (plain stores)
    float* Zbuf,             // [2][NJC][32] f32 denominators (atomic, parity)
    int* hstep,              // [32]  A-WG w: h(s) published  -> s+1
    int* estep,              // [32]  A-WG w: emb(s) published -> s+1
    int* qstep,              // [NJC*16] vocab WG: e-slice(s) published -> s+1
    int* pvstep,             // [NDC][16] (jc slot 0..13): Upart(s) published -> s+1
    float* out)
{
  const int wg = blockIdx.x;
  const int t  = threadIdx.x;
  const int wv = t >> 6;
  const int lane = t & 63;
  const int q = lane >> 4;
  const int m16 = lane & 15;

  __shared__ __align__(16) char smem[SMEM_BYTES];
  unsigned char* lds_ws   = (unsigned char*)smem;
  unsigned char* lds_e8ts = (unsigned char*)(smem + OFF_E8TS_L);
  unsigned char* lds_e    = (unsigned char*)(smem + OFF_ELDS_L);
  unsigned short* lds_wkr = (unsigned short*)smem;
  float* zbuf = (float*)(smem + OFF_ZBUF_L);

  if (wg < NA) {
    // ---------------- A-WG: LSTM owner of d-slice [wg*16, wg*16+16) ----------------
    for (int idx = t; idx < 64 * 148; idx += WG_SIZE) {
      int row = idx / 148, grp = idx - row * 148;
      int g = row >> 4, c = row & 15;
      int n = g * 512 + (wg << 4) + c;
      ulong2 v = *(const ulong2*)(WkrT + (size_t)n * 1184 + grp * 8);
      *(ulong2*)((char*)lds_wkr + row * 2384 + grp * 16) = v;
    }
    const int dl = t & 15;
    const float bias0 = bvec[0 * 512 + (wg << 4) + dl];
    const float bias1 = bvec[1 * 512 + (wg << 4) + dl];
    const float bias2 = bvec[2 * 512 + (wg << 4) + dl];
    const float bias3 = bvec[3 * 512 + (wg << 4) + dl];
    float c2[2] = {0.f, 0.f};
    __syncthreads();

    const int mt = wv & 1, g0w = (wv >> 1) << 1;
    const int row = mt * 16 + m16;
    const unsigned short* b0row = lds_wkr + (g0w * 16 + m16) * 1192;
    const unsigned short* b1row = lds_wkr + ((g0w + 1) * 16 + m16) * 1192;
    const int d = (wg << 4) + dl;
    const int dc_a = wg >> 1;                 // d-chunk this slice lives in
    const int dl32 = ((wg & 1) << 4) + dl;    // col within the 32-wide chunk

    floatx4 accG0 = {0.f, 0.f, 0.f, 0.f}, accG1 = {0.f, 0.f, 0.f, 0.f};

    for (int s = 0; s < T_STEPS; ++s) {
      const int pc = s & 1;
      if (s == 0) {
        // cs-part
#pragma unroll
        for (int ks = 16; ks < 21; ++ks) {
          bf16x8 a = *(const bf16x8*)(cs_bf + row * 160 + (ks - 16) * 32 + q * 8);
          accG0 = mfma_bf16(a, *(const bf16x8*)(b0row + ks * 32 + q * 8), accG0);
          accG1 = mfma_bf16(a, *(const bf16x8*)(b1row + ks * 32 + q * 8), accG1);
        }
        // emb from E row 0
#pragma unroll 4
        for (int ks = 0; ks < 16; ++ks) {
          const float* ep = E + ks * 32 + q * 8;
          bf16x8 a;
#pragma unroll
          for (int i = 0; i < 8; ++i) a[i] = (__bf16)ep[i];
          accG0 = mfma_bf16(a, *(const bf16x8*)(b0row + ks * 32 + q * 8), accG0);
          accG1 = mfma_bf16(a, *(const bf16x8*)(b1row + ks * 32 + q * 8), accG1);
        }
      } else {
        // all A-WGs published emb(s-1)? (acc holds h+cs parts from precompute)
        wave_spin(estep, NA, s);
#pragma unroll 8
        for (int ks = 0; ks < 16; ++ks) {
          bf16x8 a = ld_bf8_at(emb_bf + row * 512 + ks * 32 + q * 8);
          accG0 = mfma_bf16(a, *(const bf16x8*)(b0row + ks * 32 + q * 8), accG0);
          accG1 = mfma_bf16(a, *(const bf16x8*)(b1row + ks * 32 + q * 8), accG1);
        }
      }
      // --- exchange z via LDS (wave owns (gate-pair, m-tile)) ---
#pragma unroll
      for (int r = 0; r < 4; ++r) {
        zbuf[(g0w * 32 + mt * 16 + q * 4 + r) * 16 + m16] = accG0[r];
        zbuf[((g0w + 1) * 32 + mt * 16 + q * 4 + r) * 16 + m16] = accG1[r];
      }
      __syncthreads();
      // --- LSTM pointwise; stage h ---
#pragma unroll
      for (int pp = 0; pp < 2; ++pp) {
        const int b = (pp * 256 + t) >> 4;
        float zi = zbuf[(0 * 32 + b) * 16 + dl] + bias0;
        float zf = zbuf[(1 * 32 + b) * 16 + dl] + bias1;
        float zg = zbuf[(2 * 32 + b) * 16 + dl] + bias2;
        float zo = zbuf[(3 * 32 + b) * 16 + dl] + bias3;
        float iv = sigmoidf(zi), fv = sigmoidf(zf);
        float gv = tanhf(zg),    ov = sigmoidf(zo);
        c2[pp] = fv * c2[pp] + iv * gv;
        float h = ov * tanhf(c2[pp]);
        astu16(h_bufg + b * 512 + d, f2bf(h));
        astu8(h8 + b * 512 + d, f2fp8(h));
      }
      stamp_publish(hstep + wg, s + 1);   // single-writer slot
      // --- precompute h+cs part of z(s+1) (overlaps vocab logits+PV) ---
      if (s + 1 < T_STEPS) {
        wave_spin(hstep, NA, s + 1);      // all h(s) final
        accG0 = floatx4{0.f, 0.f, 0.f, 0.f};
        accG1 = floatx4{0.f, 0.f, 0.f, 0.f};
#pragma unroll 8
        for (int ks = 21; ks < 37; ++ks) {
          bf16x8 a = ld_bf8_at(h_bufg + row * 512 + (ks - 21) * 32 + q * 8);
          accG0 = mfma_bf16(a, *(const bf16x8*)(b0row + ks * 32 + q * 8), accG0);
          accG1 = mfma_bf16(a, *(const bf16x8*)(b1row + ks * 32 + q * 8), accG1);
        }
#pragma unroll
        for (int ks = 16; ks < 21; ++ks) {
          bf16x8 a = *(const bf16x8*)(cs_bf + row * 160 + (ks - 16) * 32 + q * 8);
          accG0 = mfma_bf16(a, *(const bf16x8*)(b0row + ks * 32 + q * 8), accG0);
          accG1 = mfma_bf16(a, *(const bf16x8*)(b1row + ks * 32 + q * 8), accG1);
        }
      }
      // --- ballot-incremental reduce: accumulate Upart/Z tiles as producers arrive ---
      {
        float uv[2] = {0.f, 0.f}, Zv[2] = {0.f, 0.f};
        const unsigned FULL = (1u << NJC) - 1;
        unsigned done = 0;
        while (done != FULL) {
          int v = (lane < NJC) ? aldi(pvstep + dc_a * 16 + lane) : 0x7fffffff;
          unsigned long long bal = __ballot(v >= s + 1);
          unsigned newly = ((unsigned)bal & FULL) & ~done;
          if (newly) {
            float tu[2][NJC], tz[2][NJC];
#pragma unroll
            for (int jc = 0; jc < NJC; ++jc)
              if (newly & (1u << jc)) {
#pragma unroll
                for (int pp = 0; pp < 2; ++pp) {
                  const int b = (pp * 256 + t) >> 4;
                  tu[pp][jc] = aldf(Upart + ((size_t)(dc_a * NJC + jc) * 32 + b) * 32 + dl32);
                  tz[pp][jc] = aldf(Zbuf + pc * (NJC * 32) + jc * 32 + b);
                }
              }
#pragma unroll
            for (int jc = 0; jc < NJC; ++jc)
              if (newly & (1u << jc)) {
#pragma unroll
                for (int pp = 0; pp < 2; ++pp) { uv[pp] += tu[pp][jc]; Zv[pp] += tz[pp][jc]; }
              }
            done |= newly;
          }
        }
        // --- normalize, publish emb ---
        float evs[2];
#pragma unroll
        for (int pp = 0; pp < 2; ++pp) {
          const int b = (pp * 256 + t) >> 4;
          float ev = uv[pp] / Zv[pp];
          evs[pp] = ev;
          astu16(emb_bf + b * 512 + d, f2bf(ev));
        }
        // zero the Z parity consumed at step s-1 (all readers done: estep>=s observed)
        if (s >= 1 && t < NJC) astf(Zbuf + ((s - 1) & 1) * (NJC * 32) + t * 32 + wg, 0.0f);
        stamp_publish(estep + wg, s + 1);
        // --- deferred out stores (pure sink, off the critical chain) ---
#pragma unroll
        for (int pp = 0; pp < 2; ++pp) {
          const int b = (pp * 256 + t) >> 4;
          out[(size_t)b * (64 * 512) + (size_t)(s + 1) * 512 + d] = evs[pp];
        }
      }
    }
  } else {
    // ---------------- vocab WG ----------------
    const int wgv = wg - NA;
    const int jc = wgv >> 4;          // j-chunk (2304 words)
    const int dc = wgv & 15;          // d-chunk (32 cols) this WG reduces in PV
    const long j0 = (long)wgv * 144;  // own 144-word logits slice
    // Ws^T slice -> LDS
    for (int idx = t; idx < 144 * 64; idx += WG_SIZE) {
      int r2 = idx >> 6, grp = idx & 63;
      long v = *(const long*)(Ws8_g + (j0 + r2) * 512 + grp * 8);
      *(long*)(lds_ws + r2 * 512 + ((grp ^ (r2 & 7)) << 3)) = v;
    }
    // E^T slice [32 d][2304 j] -> LDS, rotated by d-row
    for (int idx = t; idx < 32 * 288; idx += WG_SIZE) {
      int dd = idx / 288, g = idx - dd * 288;
      long v = *(const long*)(E8T_g + (size_t)(dc * 32 + dd) * 32768 + (size_t)jc * 2304 + (size_t)g * 8);
      int g2 = g + dd; if (g2 >= 288) g2 -= 288;
      *(long*)(lds_e8ts + dd * 2304 + (g2 << 3)) = v;
    }
    __syncthreads();

    for (int s = 0; s < T_STEPS; ++s) {
      wave_spin(hstep, NA, s + 1);      // all h(s) published
      const int pc = s & 1;
      long ah[2][16];
#pragma unroll
      for (int mtl = 0; mtl < 2; ++mtl)
#pragma unroll
        for (int ks = 0; ks < 16; ++ks)
          ah[mtl][ks] = (long)ald64(h8 + (mtl * 16 + m16) * 512 + ks * 32 + q * 8);
      // logits: 9 n-tiles round-robin over waves
      for (int tile = wv; tile < 9; tile += 4) {
        const int jl = tile * 16 + m16;
        const unsigned char* wrow = lds_ws + jl * 512;
        const int sw = jl & 7;
        floatx4 acc[2] = {{0,0,0,0},{0,0,0,0}};
#pragma unroll
        for (int ks = 0; ks < 16; ++ks) {
          int g = ks * 4 + q;
          long bfrag = *(const long*)(wrow + ((g ^ sw) << 3));
          acc[0] = mfma_fp8(ah[0][ks], bfrag, acc[0]);
          acc[1] = mfma_fp8(ah[1][ks], bfrag, acc[1]);
        }
        const long jg = j0 + jl;
        const float bsv = bs[jg < 32000 ? jg : 31999];
        const bool valid = (jg < 32000);
#pragma unroll
        for (int mtl = 0; mtl < 2; ++mtl)
#pragma unroll
          for (int r = 0; r < 4; ++r) {
            float e = valid ? __expf(acc[mtl][r] + bsv) : 0.0f;
            lds_e[(mtl * 16 + q * 4 + r) * 160 + jl] = f2fp8(e);
          }
      }
      __syncthreads();
      // publish e slice (waves 0-2) IN PARALLEL with Z partial (wave 3);
      // both drained by the qstep stamp -> transitive ordering via qstep->pvstep intact
      if (t < 192) {
#pragma unroll
        for (int k6 = 0; k6 < 6; ++k6) {
          int idx = k6 * 192 + t;     // 0..1151
          int b = idx / 36, g = idx - b * 36;
          unsigned int v = *(const unsigned int*)(lds_e + b * 160 + g * 4);
          astu32((unsigned int*)(e8g + (size_t)b * 32768 + j0 + g * 4), v);
        }
      } else if (t < 224) {
        const int b = t - 192;
        const unsigned int* rowp = (const unsigned int*)(lds_e + b * 160);
        float z = 0.f;
        for (int g = 0; g < 36; ++g) {
          int w4 = (int)rowp[g];
          z += __builtin_amdgcn_cvt_f32_fp8(w4, 0) + __builtin_amdgcn_cvt_f32_fp8(w4, 1)
             + __builtin_amdgcn_cvt_f32_fp8(w4, 2) + __builtin_amdgcn_cvt_f32_fp8(w4, 3);
        }
        afaddf(Zbuf + pc * (NJC * 32) + jc * 32 + b, z);
      }
      stamp_publish(qstep + wgv, s + 1);
      // group readiness: 16 producers of chunk jc
      wave_spin(qstep + jc * 16, 16, s + 1);
      // --- PV: full partial e[:, jc-chunk] @ E[jc-chunk, dc*32..+32] ---
      {
        const int mtp = wv & 1, ntl = wv >> 1;
        const int dl_local = ntl * 16 + m16;
        const unsigned char* erow = lds_e8ts + dl_local * 2304;
        const unsigned char* arow = e8g + (size_t)(mtp * 16 + m16) * 32768 + (size_t)jc * 2304;
        floatx4 acc0 = {0,0,0,0}, acc1 = {0,0,0,0};
#pragma unroll 8
        for (int ks = 0; ks < 72; ks += 2) {
          long a0 = (long)ald64(arow + ks * 32 + q * 8);
          long a1 = (long)ald64(arow + (ks + 1) * 32 + q * 8);
          int g0i = ks * 4 + q + dl_local; if (g0i >= 288) g0i -= 288;
          int g1i = g0i + 4;               if (g1i >= 288) g1i -= 288;
          acc0 = mfma_fp8(a0, *(const long*)(erow + (g0i << 3)), acc0);
          acc1 = mfma_fp8(a1, *(const long*)(erow + (g1i << 3)), acc1);
        }
        floatx4 accs = acc0 + acc1;
#pragma unroll
        for (int r = 0; r < 4; ++r)
          astf(Upart + ((size_t)(dc * NJC + jc) * 32 + (mtp * 16 + (q << 2) + r)) * 32 + dl_local, accs[r]);
      }
      stamp_publish(pvstep + dc * 16 + jc, s + 1);
    }
  }
}

// ---------------- host ----------------
extern "C" void kernel_launch(void* const* d_in, const int* in_sizes, int n_in,
                              void* d_out, int out_size, void* d_ws, size_t ws_size,
                              hipStream_t stream) {
  const float* content = (const float*)d_in[0];
  const float* style   = (const float*)d_in[1];
  const float* E       = (const float*)d_in[2];
  const float* Wk      = (const float*)d_in[3];
  const float* Wr      = (const float*)d_in[4];
  const float* bvec    = (const float*)d_in[5];
  const float* Ws      = (const float*)d_in[6];
  const float* bs      = (const float*)d_in[7];
  float* out = (float*)d_out;
  char* ws = (char*)d_ws;

  constexpr size_t SZ_WS8  = 32256ull * 512;             // 16,515,072
  constexpr size_t SZ_E8T  = 512ull * 32768;             // 16,777,216
  constexpr size_t SZ_WKRT = 2048ull * 1184 * 2;         //  4,849,664
  constexpr size_t SZ_CS   = 32ull * 160 * 2;            //     10,240
  constexpr size_t SZ_HB   = 32ull * 512 * 2;            //     32,768
  constexpr size_t SZ_H8   = 32ull * 512;                //     16,384
  constexpr size_t SZ_EMB  = 32ull * 512 * 2;            //     32,768
  constexpr size_t SZ_E8G  = 32ull * 32768;              //  1,048,576
  constexpr size_t SZ_UP   = 16ull * 14 * 32 * 32 * 4;   //    917,504
  constexpr size_t SZ_ZB   = 2ull * NJC * 32 * 4;        //      3,584
  constexpr size_t SZ_HS   = 64ull * 4;                  //        256 (32 used)
  constexpr size_t SZ_ES   = 64ull * 4;                  //        256 (32 used)
  constexpr size_t SZ_QS   = 256ull * 4;                 //      1,024 (224 used)
  constexpr size_t SZ_PS   = 256ull * 4;                 //      1,024 (16*14 used)

  constexpr size_t OFF_WS8  = 0;
  constexpr size_t OFF_E8T  = OFF_WS8 + SZ_WS8;
  constexpr size_t OFF_WKRT = OFF_E8T + SZ_E8T;
  constexpr size_t OFF_CS   = OFF_WKRT + SZ_WKRT;
  constexpr size_t OFF_HB   = OFF_CS + SZ_CS;
  constexpr size_t OFF_H8   = OFF_HB + SZ_HB;
  constexpr size_t OFF_EMB  = OFF_H8 + SZ_H8;
  constexpr size_t OFF_E8G  = OFF_EMB + SZ_EMB;
  constexpr size_t OFF_UP   = OFF_E8G + SZ_E8G;
  constexpr size_t OFF_ZB   = OFF_UP + SZ_UP;
  constexpr size_t OFF_HS   = OFF_ZB + SZ_ZB;
  constexpr size_t OFF_ES   = OFF_HS + SZ_HS;
  constexpr size_t OFF_QS   = OFF_ES + SZ_ES;
  constexpr size_t OFF_PS   = OFF_QS + SZ_QS;

  unsigned char*  Ws8_g = (unsigned char*)(ws + OFF_WS8);
  unsigned char*  E8T_g = (unsigned char*)(ws + OFF_E8T);
  unsigned short* WkrT  = (unsigned short*)(ws + OFF_WKRT);
  unsigned short* cs_bf = (unsigned short*)(ws + OFF_CS);
  unsigned short* h_bufg= (unsigned short*)(ws + OFF_HB);
  unsigned char*  h8    = (unsigned char*)(ws + OFF_H8);
  unsigned short* emb_bf= (unsigned short*)(ws + OFF_EMB);
  unsigned char*  e8g   = (unsigned char*)(ws + OFF_E8G);
  float* Upart          = (float*)(ws + OFF_UP);
  float* Zbuf           = (float*)(ws + OFF_ZB);
  int* hstep            = (int*)(ws + OFF_HS);
  int* estep            = (int*)(ws + OFF_ES);
  int* qstep            = (int*)(ws + OFF_QS);
  int* pvstep           = (int*)(ws + OFF_PS);

  // zero state (ws poisoned each call)
  hipMemsetAsync(Ws8_g, 0, SZ_WS8, stream);
  hipMemsetAsync(E8T_g, 0, SZ_E8T, stream);
  hipMemsetAsync(WkrT, 0, SZ_WKRT, stream);
  hipMemsetAsync(ws + OFF_ZB, 0, SZ_ZB + SZ_HS + SZ_ES + SZ_QS + SZ_PS, stream);

  // transposed weight copies; Wkr k-layout = Wk(656) | pad16 | Wr(512)
  k_transpose_fp8<<<dim3(8, 500), 256, 0, stream>>>(Ws, Ws8_g, 512, 32000, 512);
  k_transpose_fp8<<<dim3(500, 8), 256, 0, stream>>>(E, E8T_g, 32000, 512, 32768);
  k_transpose<<<dim3(11, 32), 256, 0, stream>>>(Wk, WkrT, 656, 2048, 1184, 0);
  k_transpose<<<dim3(8, 32), 256, 0, stream>>>(Wr, WkrT, 512, 2048, 1184, 672);
  k_init<<<64, 256, 0, stream>>>(content, style, E, cs_bf, out);

  void* args[] = { (void*)&bvec, (void*)&bs, (void*)&Ws8_g, (void*)&E8T_g, (void*)&WkrT,
                   (void*)&cs_bf, (void*)&E, (void*)&h_bufg, (void*)&h8, (void*)&emb_bf,
                   (void*)&e8g, (void*)&Upart, (void*)&Zbuf,
                   (void*)&hstep, (void*)&estep, (void*)&qstep, (void*)&pvstep,
                   (void*)&out };
  hipLaunchCooperativeKernel((void*)k_main, dim3(NWG), dim3(WG_SIZE), args, 0, stream);

  (void)in_sizes; (void)n_in; (void)out_size; (void)ws_size;
}